// Round 4
// baseline (363.771 us; speedup 1.0000x reference)
//
#include <hip/hip_runtime.h>

// y[i] = W2[i] . relu(x[i]*W1[i] + b1[i]) + b2[i],  H=8, all fp32.
// Streaming, 104 B in + 4 B out per element. MLP-bound fix: batch 4
// elements' loads per thread (all issued before any use) to quadruple
// outstanding bytes per wave.
//
// Layout: 2 lanes per element. Lane-slot f in [0, 2N) owns float4 #f of
// W1/b1/W2 (viewed as [2N] float4). Thread t handles slots f = t + u*tcount,
// u = 0..U-1 — consecutive t -> consecutive f in every instruction, so all
// loads are perfectly coalesced. Pair lanes (f even/odd, == t even/odd since
// tcount is even) combine via one shfl_xor.

constexpr int U = 4;

__global__ __launch_bounds__(256) void tiny_mlp_kernel(
    const float*  __restrict__ x,    // [N]
    const float4* __restrict__ W1v,  // [2N]
    const float4* __restrict__ b1v,  // [2N]
    const float4* __restrict__ W2v,  // [2N]
    const float*  __restrict__ b2,   // [N]
    float*        __restrict__ y,    // [N]
    int tcount)                      // = 2N / U  (even)
{
    const int t = blockIdx.x * blockDim.x + threadIdx.x;
    if (t >= tcount) return;

    // ---- issue ALL loads first (12 dwordx4 + 8 dword) ----
    float4 w1[U], c1[U], w2[U];
    float  xv[U], bv[U];
    #pragma unroll
    for (int u = 0; u < U; ++u) w1[u] = W1v[t + u * tcount];
    #pragma unroll
    for (int u = 0; u < U; ++u) c1[u] = b1v[t + u * tcount];
    #pragma unroll
    for (int u = 0; u < U; ++u) w2[u] = W2v[t + u * tcount];
    #pragma unroll
    for (int u = 0; u < U; ++u) xv[u] = x[(t + u * tcount) >> 1];
    #pragma unroll
    for (int u = 0; u < U; ++u) bv[u] = b2[(t + u * tcount) >> 1];

    // ---- compute + store ----
    #pragma unroll
    for (int u = 0; u < U; ++u) {
        const float  xi = xv[u];
        const float4 a  = w1[u];
        const float4 c  = c1[u];
        const float4 w  = w2[u];

        const float h0 = fmaxf(fmaf(xi, a.x, c.x), 0.0f);
        const float h1 = fmaxf(fmaf(xi, a.y, c.y), 0.0f);
        const float h2 = fmaxf(fmaf(xi, a.z, c.z), 0.0f);
        const float h3 = fmaxf(fmaf(xi, a.w, c.w), 0.0f);

        float p = h0 * w.x;
        p = fmaf(h1, w.y, p);
        p = fmaf(h2, w.z, p);
        p = fmaf(h3, w.w, p);

        p += __shfl_xor(p, 1);  // combine element halves (lanes t, t^1)

        if ((t & 1) == 0) {
            y[(t + u * tcount) >> 1] = p + bv[u];
        }
    }
}

// Fallback single-slot kernel for any remainder slots (unused when 2N % U == 0).
__global__ __launch_bounds__(256) void tiny_mlp_tail(
    const float*  __restrict__ x,
    const float4* __restrict__ W1v,
    const float4* __restrict__ b1v,
    const float4* __restrict__ W2v,
    const float*  __restrict__ b2,
    float*        __restrict__ y,
    int fbase, int n2)
{
    const int f = fbase + blockIdx.x * blockDim.x + threadIdx.x;
    if (f >= n2) return;
    const int i = f >> 1;
    const float  xi = x[i];
    const float4 a  = W1v[f];
    const float4 c  = b1v[f];
    const float4 w  = W2v[f];
    const float h0 = fmaxf(fmaf(xi, a.x, c.x), 0.0f);
    const float h1 = fmaxf(fmaf(xi, a.y, c.y), 0.0f);
    const float h2 = fmaxf(fmaf(xi, a.z, c.z), 0.0f);
    const float h3 = fmaxf(fmaf(xi, a.w, c.w), 0.0f);
    float p = h0 * w.x;
    p = fmaf(h1, w.y, p);
    p = fmaf(h2, w.z, p);
    p = fmaf(h3, w.w, p);
    p += __shfl_xor(p, 1);
    if ((f & 1) == 0) y[i] = p + b2[i];
}

extern "C" void kernel_launch(void* const* d_in, const int* in_sizes, int n_in,
                              void* d_out, int out_size, void* d_ws, size_t ws_size,
                              hipStream_t stream) {
    const float*  x  = (const float*) d_in[0];
    const float4* W1 = (const float4*)d_in[1];
    const float4* b1 = (const float4*)d_in[2];
    const float4* W2 = (const float4*)d_in[3];
    const float*  b2 = (const float*) d_in[4];
    float*        y  = (float*)d_out;

    const int n  = in_sizes[0];  // N
    const int n2 = 2 * n;        // lane-slots

    const int block  = 256;
    int tcount = n2 / U;         // slots handled by the main kernel per u
    if (tcount & 1) tcount -= 1; // keep even so pair lanes stay adjacent
    const int covered = tcount * U;

    if (tcount > 0) {
        const int grid = (tcount + block - 1) / block;
        tiny_mlp_kernel<<<grid, block, 0, stream>>>(x, W1, b1, W2, b2, y, tcount);
    }
    if (covered < n2) {  // remainder slots (none for N = 4M)
        const int rem  = n2 - covered;
        const int grid = (rem + block - 1) / block;
        tiny_mlp_tail<<<grid, block, 0, stream>>>(x, W1, b1, W2, b2, y, covered, n2);
    }
}